// Round 1
// baseline (294.259 us; speedup 1.0000x reference)
//
#include <hip/hip_runtime.h>
#include <math.h>

#define N_NODES 10000
#define N_EDGES 640000
#define N_GRAPHS 64
#define DIM 128
#define NEG_SLOPE 0.01f

// ---------------- workspace layout (bytes) ----------------
// feat   : 0          .. 10,240,000   float[2][10000][128]
// resid  : 10,240,000 .. 20,480,000   float[2][10000][128]
// a_self : 20,480,000                 float[2][10000]
// a_nb   : 20,560,000                 float[2][10000]
// deg    : 20,640,000                 int[10000]
// rowptr : 20,688,000                 int[10001]
// cursor : 20,736,000                 int[10000]
// csr_src: 20,784,000                 int[640000]
// total  : 23,344,000

// ---------------- CSR build ----------------
__global__ void count_deg(const int* __restrict__ edst, int* __restrict__ deg) {
    int e = blockIdx.x * blockDim.x + threadIdx.x;
    if (e < N_EDGES) atomicAdd(&deg[edst[e]], 1);
}

__global__ __launch_bounds__(1024) void scan_deg(const int* __restrict__ deg,
                                                 int* __restrict__ rowptr,
                                                 int* __restrict__ cursor) {
    __shared__ int sdata[1024];
    const int tid = threadIdx.x;
    const int base = tid * 10;
    int cnt = N_NODES - base;
    if (cnt < 0) cnt = 0;
    if (cnt > 10) cnt = 10;
    int local[10];
    int s = 0;
    for (int i = 0; i < cnt; ++i) { local[i] = s; s += deg[base + i]; }
    sdata[tid] = s;
    __syncthreads();
    for (int off = 1; off < 1024; off <<= 1) {
        int v = 0;
        if (tid >= off) v = sdata[tid - off];
        __syncthreads();
        if (tid >= off) sdata[tid] += v;
        __syncthreads();
    }
    int pre = (tid == 0) ? 0 : sdata[tid - 1];
    for (int i = 0; i < cnt; ++i) {
        int v = pre + local[i];
        rowptr[base + i] = v;
        cursor[base + i] = v;
    }
    if (tid == 1023) rowptr[N_NODES] = sdata[1023];
}

__global__ void scatter_edges(const int* __restrict__ esrc, const int* __restrict__ edst,
                              int* __restrict__ cursor, int* __restrict__ csr_src) {
    int e = blockIdx.x * blockDim.x + threadIdx.x;
    if (e < N_EDGES) {
        int d = edst[e];
        int pos = atomicAdd(&cursor[d], 1);
        csr_src[pos] = esrc[e];
    }
}

// ---------------- GEMM: out[n][j] = sum_k x[n][k]*W[j][k] (+bias) ----------------
// grid (ceil(N/64), 2, 4), block 256.  z: bit0 = which (0=feat,1=resid), bit1 = gat block
__global__ __launch_bounds__(256) void gemm_xwT(
    const float* __restrict__ x, const float* __restrict__ Wfc,
    const float* __restrict__ bfc, const float* __restrict__ Wres,
    float* __restrict__ feat, float* __restrict__ resid) {
    const int which = blockIdx.z & 1;
    const int b = blockIdx.z >> 1;
    const float* __restrict__ W = (which ? Wres : Wfc) + b * DIM * DIM;
    float* __restrict__ out = (which ? resid : feat) + (size_t)b * N_NODES * DIM;
    const int n0 = blockIdx.x * 64;
    const int j0 = blockIdx.y * 64;

    __shared__ float xs[32][68];   // [k][node], padded (stride 68 floats = 16B-aligned rows)
    __shared__ float wsh[32][68];  // [k][col]

    const int t = threadIdx.x;
    const int tj = t & 15;   // col group
    const int tn = t >> 4;   // node group
    const int r = t >> 2;    // staging row 0..63
    const int q = t & 3;     // staging col quarter

    float acc[4][4];
#pragma unroll
    for (int i = 0; i < 4; ++i)
#pragma unroll
        for (int j = 0; j < 4; ++j) acc[i][j] = 0.f;

    for (int kc = 0; kc < DIM; kc += 32) {
        // stage x tile (64 nodes x 32 k), transposed into xs[k][n]
        {
            float v[8];
            int n = n0 + r;
            if (n < N_NODES) {
                const float* p = x + (size_t)n * DIM + kc + q * 8;
                float4 v0 = *reinterpret_cast<const float4*>(p);
                float4 v1 = *reinterpret_cast<const float4*>(p + 4);
                v[0] = v0.x; v[1] = v0.y; v[2] = v0.z; v[3] = v0.w;
                v[4] = v1.x; v[5] = v1.y; v[6] = v1.z; v[7] = v1.w;
            } else {
#pragma unroll
                for (int m = 0; m < 8; ++m) v[m] = 0.f;
            }
#pragma unroll
            for (int m = 0; m < 8; ++m) xs[q * 8 + m][r] = v[m];

            const float* pw = W + (size_t)(j0 + r) * DIM + kc + q * 8;
            float4 w0 = *reinterpret_cast<const float4*>(pw);
            float4 w1 = *reinterpret_cast<const float4*>(pw + 4);
            float wv[8] = {w0.x, w0.y, w0.z, w0.w, w1.x, w1.y, w1.z, w1.w};
#pragma unroll
            for (int m = 0; m < 8; ++m) wsh[q * 8 + m][r] = wv[m];
        }
        __syncthreads();

#pragma unroll
        for (int k = 0; k < 32; ++k) {
            float4 xv = *reinterpret_cast<const float4*>(&xs[k][4 * tn]);
            float4 wv = *reinterpret_cast<const float4*>(&wsh[k][4 * tj]);
            float xa[4] = {xv.x, xv.y, xv.z, xv.w};
            float wa[4] = {wv.x, wv.y, wv.z, wv.w};
#pragma unroll
            for (int i = 0; i < 4; ++i)
#pragma unroll
                for (int j = 0; j < 4; ++j) acc[i][j] += xa[i] * wa[j];
        }
        __syncthreads();
    }

    // epilogue
#pragma unroll
    for (int i = 0; i < 4; ++i) {
        int n = n0 + tn * 4 + i;
        if (n < N_NODES) {
            int j = j0 + tj * 4;
            float4 o;
            o.x = acc[i][0]; o.y = acc[i][1]; o.z = acc[i][2]; o.w = acc[i][3];
            if (!which) {
                const float* bias = bfc + b * DIM + j;
                o.x += bias[0]; o.y += bias[1]; o.z += bias[2]; o.w += bias[3];
            }
            *reinterpret_cast<float4*>(out + (size_t)n * DIM + j) = o;
        }
    }
}

// ---------------- per-node attention scalars ----------------
// grid (2500, 2), block 256 (4 waves, one node each)
__global__ __launch_bounds__(256) void a_compute(
    const float* __restrict__ feat, const float* __restrict__ wl,
    const float* __restrict__ wr, float* __restrict__ a_self,
    float* __restrict__ a_nb) {
    const int wave = threadIdx.x >> 6;
    const int lane = threadIdx.x & 63;
    const int n = blockIdx.x * 4 + wave;
    const int b = blockIdx.y;
    if (n >= N_NODES) return;
    const float* fr = feat + ((size_t)b * N_NODES + n) * DIM;
    float f0 = fr[lane], f1 = fr[lane + 64];
    float sv = f0 * wl[b * DIM + lane] + f1 * wl[b * DIM + lane + 64];
    float rv = f0 * wr[b * DIM + lane] + f1 * wr[b * DIM + lane + 64];
#pragma unroll
    for (int off = 32; off > 0; off >>= 1) {
        sv += __shfl_down(sv, off, 64);
        rv += __shfl_down(rv, off, 64);
    }
    if (lane == 0) {
        a_self[b * N_NODES + n] = sv;
        a_nb[b * N_NODES + n] = rv;
    }
}

// ---------------- softmax + weighted aggregation + residual + relu ----------------
// grid (N_NODES, 2), block 128
__global__ __launch_bounds__(128) void aggregate(
    const float* __restrict__ feat, const float* __restrict__ resid,
    const float* __restrict__ a_self, const float* __restrict__ a_nb,
    const int* __restrict__ rowptr, const int* __restrict__ csr_src,
    float* __restrict__ out) {
    const int n = blockIdx.x;
    const int b = blockIdx.y;
    const int tid = threadIdx.x;
    const int start = rowptr[n];
    const int end = rowptr[n + 1];

    __shared__ float red[128];
    __shared__ float eL[128];
    __shared__ int sL[128];

    const float* __restrict__ anb = a_nb + b * N_NODES;
    const float* __restrict__ featb = feat + (size_t)b * N_NODES * DIM;
    const float asl = a_self[b * N_NODES + n];

    // pass A: segment max
    float m = -INFINITY;
    for (int j = start + tid; j < end; j += 128) {
        float s = asl + anb[csr_src[j]];
        s = (s >= 0.f) ? s : NEG_SLOPE * s;
        m = fmaxf(m, s);
    }
    red[tid] = m;
    __syncthreads();
#pragma unroll
    for (int s2 = 64; s2 > 0; s2 >>= 1) {
        if (tid < s2) red[tid] = fmaxf(red[tid], red[tid + s2]);
        __syncthreads();
    }
    m = red[0];

    // pass B: chunked exp + weighted gather
    float acc = 0.f, denom = 0.f;
    for (int c = start; c < end; c += 128) {
        int j = c + tid;
        float e = 0.f;
        int srcj = 0;
        if (j < end) {
            srcj = csr_src[j];
            float s = asl + anb[srcj];
            s = (s >= 0.f) ? s : NEG_SLOPE * s;
            e = __expf(s - m);
        }
        __syncthreads();
        eL[tid] = e;
        sL[tid] = srcj;
        __syncthreads();
        int cnt = end - c;
        if (cnt > 128) cnt = 128;
        for (int i = 0; i < cnt; ++i) {
            float w = eL[i];
            denom += w;
            acc += w * featb[(size_t)sL[i] * DIM + tid];
        }
    }

    float resv = resid[((size_t)b * N_NODES + n) * DIM + tid];
    float v = (end > start) ? (acc / denom) : 0.f;
    v += resv;
    v = fmaxf(v, 0.f);
    out[(size_t)n * (2 * DIM) + b * DIM + tid] = v;
}

// ---------------- per-graph sum pooling ----------------
__device__ int lower_bound_dev(const int* __restrict__ a, int n, int key) {
    int lo = 0, hi = n;
    while (lo < hi) {
        int mid = (lo + hi) >> 1;
        if (a[mid] < key) lo = mid + 1;
        else hi = mid;
    }
    return lo;
}

// grid N_GRAPHS, block 256
__global__ __launch_bounds__(256) void pool_graphs(
    const float* __restrict__ h, const int* __restrict__ gids,
    float* __restrict__ phis) {
    const int g = blockIdx.x;
    const int tid = threadIdx.x;
    int lo = lower_bound_dev(gids, N_NODES, g);
    int hi = lower_bound_dev(gids, N_NODES, g + 1);
    float acc = 0.f;
    for (int n = lo; n < hi; ++n) acc += h[(size_t)n * (2 * DIM) + tid];
    phis[(size_t)g * (2 * DIM) + tid] = acc;
}

extern "C" void kernel_launch(void* const* d_in, const int* in_sizes, int n_in,
                              void* d_out, int out_size, void* d_ws, size_t ws_size,
                              hipStream_t stream) {
    const float* x    = (const float*)d_in[0];
    const int* esrc   = (const int*)d_in[1];
    const int* edst   = (const int*)d_in[2];
    const int* gids   = (const int*)d_in[3];
    const float* Wfc  = (const float*)d_in[4];
    const float* bfc  = (const float*)d_in[5];
    const float* wl   = (const float*)d_in[6];
    const float* wr   = (const float*)d_in[7];
    const float* Wres = (const float*)d_in[8];
    float* out = (float*)d_out;

    char* ws = (char*)d_ws;
    float* feat    = (float*)(ws + 0);
    float* resid   = (float*)(ws + 10240000);
    float* a_self  = (float*)(ws + 20480000);
    float* a_nb    = (float*)(ws + 20560000);
    int*   deg     = (int*)(ws + 20640000);
    int*   rowptr  = (int*)(ws + 20688000);
    int*   cursor  = (int*)(ws + 20736000);
    int*   csr_src = (int*)(ws + 20784000);

    hipMemsetAsync(deg, 0, N_NODES * sizeof(int), stream);
    count_deg<<<(N_EDGES + 255) / 256, 256, 0, stream>>>(edst, deg);
    scan_deg<<<1, 1024, 0, stream>>>(deg, rowptr, cursor);
    scatter_edges<<<(N_EDGES + 255) / 256, 256, 0, stream>>>(esrc, edst, cursor, csr_src);

    gemm_xwT<<<dim3((N_NODES + 63) / 64, 2, 4), 256, 0, stream>>>(x, Wfc, bfc, Wres, feat, resid);
    a_compute<<<dim3((N_NODES + 3) / 4, 2), 256, 0, stream>>>(feat, wl, wr, a_self, a_nb);
    aggregate<<<dim3(N_NODES, 2), 128, 0, stream>>>(feat, resid, a_self, a_nb, rowptr, csr_src, out);
    pool_graphs<<<N_GRAPHS, 256, 0, stream>>>(out, gids, out + (size_t)N_NODES * 2 * DIM);
}

// Round 2
// 288.667 us; speedup vs baseline: 1.0194x; 1.0194x over previous
//
#include <hip/hip_runtime.h>
#include <math.h>

#define N_NODES 10000
#define N_EDGES 640000
#define N_GRAPHS 64
#define DIM 128
#define NEG_SLOPE 0.01f

// ---------------- workspace layout (bytes) ----------------
// feat   : 0          .. 10,240,000   float[2][10000][128]
// resid  : 10,240,000 .. 20,480,000   float[2][10000][128]
// a_self : 20,480,000                 float[2][10000]
// a_nb   : 20,560,000                 float[2][10000]
// deg    : 20,640,000                 int[10000]
// rowptr : 20,688,000                 int[10001]
// cursor : 20,736,000                 int[10000]
// csr_src: 20,784,000                 int[640000]

// ---------------- CSR build ----------------
__global__ void count_deg(const int4* __restrict__ edst4, int* __restrict__ deg) {
    int t = blockIdx.x * blockDim.x + threadIdx.x;
    if (t < N_EDGES / 4) {
        int4 d = edst4[t];
        atomicAdd(&deg[d.x], 1);
        atomicAdd(&deg[d.y], 1);
        atomicAdd(&deg[d.z], 1);
        atomicAdd(&deg[d.w], 1);
    }
}

__global__ __launch_bounds__(1024) void scan_deg(const int* __restrict__ deg,
                                                 int* __restrict__ rowptr,
                                                 int* __restrict__ cursor) {
    __shared__ int sdata[1024];
    const int tid = threadIdx.x;
    const int base = tid * 10;
    int cnt = N_NODES - base;
    if (cnt < 0) cnt = 0;
    if (cnt > 10) cnt = 10;
    int local[10];
    int s = 0;
    for (int i = 0; i < cnt; ++i) { local[i] = s; s += deg[base + i]; }
    sdata[tid] = s;
    __syncthreads();
    for (int off = 1; off < 1024; off <<= 1) {
        int v = 0;
        if (tid >= off) v = sdata[tid - off];
        __syncthreads();
        if (tid >= off) sdata[tid] += v;
        __syncthreads();
    }
    int pre = (tid == 0) ? 0 : sdata[tid - 1];
    for (int i = 0; i < cnt; ++i) {
        int v = pre + local[i];
        rowptr[base + i] = v;
        cursor[base + i] = v;
    }
    if (tid == 1023) rowptr[N_NODES] = sdata[1023];
}

__global__ void scatter_edges(const int4* __restrict__ esrc4, const int4* __restrict__ edst4,
                              int* __restrict__ cursor, int* __restrict__ csr_src) {
    int t = blockIdx.x * blockDim.x + threadIdx.x;
    if (t < N_EDGES / 4) {
        int4 s = esrc4[t];
        int4 d = edst4[t];
        csr_src[atomicAdd(&cursor[d.x], 1)] = s.x;
        csr_src[atomicAdd(&cursor[d.y], 1)] = s.y;
        csr_src[atomicAdd(&cursor[d.z], 1)] = s.z;
        csr_src[atomicAdd(&cursor[d.w], 1)] = s.w;
    }
}

// ---------------- GEMM: out[n][j] = sum_k x[n][k]*W[j][k] (+bias) ----------------
// grid (ceil(N/64), 2, 4), block 256.  z: bit0 = which (0=feat,1=resid), bit1 = gat block
__global__ __launch_bounds__(256) void gemm_xwT(
    const float* __restrict__ x, const float* __restrict__ Wfc,
    const float* __restrict__ bfc, const float* __restrict__ Wres,
    float* __restrict__ feat, float* __restrict__ resid) {
    const int which = blockIdx.z & 1;
    const int b = blockIdx.z >> 1;
    const float* __restrict__ W = (which ? Wres : Wfc) + b * DIM * DIM;
    float* __restrict__ out = (which ? resid : feat) + (size_t)b * N_NODES * DIM;
    const int n0 = blockIdx.x * 64;
    const int j0 = blockIdx.y * 64;

    __shared__ float xs[32][68];
    __shared__ float wsh[32][68];

    const int t = threadIdx.x;
    const int tj = t & 15;
    const int tn = t >> 4;
    const int r = t >> 2;
    const int q = t & 3;

    float acc[4][4];
#pragma unroll
    for (int i = 0; i < 4; ++i)
#pragma unroll
        for (int j = 0; j < 4; ++j) acc[i][j] = 0.f;

    for (int kc = 0; kc < DIM; kc += 32) {
        {
            float v[8];
            int n = n0 + r;
            if (n < N_NODES) {
                const float* p = x + (size_t)n * DIM + kc + q * 8;
                float4 v0 = *reinterpret_cast<const float4*>(p);
                float4 v1 = *reinterpret_cast<const float4*>(p + 4);
                v[0] = v0.x; v[1] = v0.y; v[2] = v0.z; v[3] = v0.w;
                v[4] = v1.x; v[5] = v1.y; v[6] = v1.z; v[7] = v1.w;
            } else {
#pragma unroll
                for (int m = 0; m < 8; ++m) v[m] = 0.f;
            }
#pragma unroll
            for (int m = 0; m < 8; ++m) xs[q * 8 + m][r] = v[m];

            const float* pw = W + (size_t)(j0 + r) * DIM + kc + q * 8;
            float4 w0 = *reinterpret_cast<const float4*>(pw);
            float4 w1 = *reinterpret_cast<const float4*>(pw + 4);
            float wv[8] = {w0.x, w0.y, w0.z, w0.w, w1.x, w1.y, w1.z, w1.w};
#pragma unroll
            for (int m = 0; m < 8; ++m) wsh[q * 8 + m][r] = wv[m];
        }
        __syncthreads();

#pragma unroll
        for (int k = 0; k < 32; ++k) {
            float4 xv = *reinterpret_cast<const float4*>(&xs[k][4 * tn]);
            float4 wv = *reinterpret_cast<const float4*>(&wsh[k][4 * tj]);
            float xa[4] = {xv.x, xv.y, xv.z, xv.w};
            float wa[4] = {wv.x, wv.y, wv.z, wv.w};
#pragma unroll
            for (int i = 0; i < 4; ++i)
#pragma unroll
                for (int j = 0; j < 4; ++j) acc[i][j] += xa[i] * wa[j];
        }
        __syncthreads();
    }

#pragma unroll
    for (int i = 0; i < 4; ++i) {
        int n = n0 + tn * 4 + i;
        if (n < N_NODES) {
            int j = j0 + tj * 4;
            float4 o;
            o.x = acc[i][0]; o.y = acc[i][1]; o.z = acc[i][2]; o.w = acc[i][3];
            if (!which) {
                const float* bias = bfc + b * DIM + j;
                o.x += bias[0]; o.y += bias[1]; o.z += bias[2]; o.w += bias[3];
            }
            *reinterpret_cast<float4*>(out + (size_t)n * DIM + j) = o;
        }
    }
}

// ---------------- per-node attention scalars ----------------
__global__ __launch_bounds__(256) void a_compute(
    const float* __restrict__ feat, const float* __restrict__ wl,
    const float* __restrict__ wr, float* __restrict__ a_self,
    float* __restrict__ a_nb) {
    const int wave = threadIdx.x >> 6;
    const int lane = threadIdx.x & 63;
    const int n = blockIdx.x * 4 + wave;
    const int b = blockIdx.y;
    if (n >= N_NODES) return;
    const float* fr = feat + ((size_t)b * N_NODES + n) * DIM;
    float f0 = fr[lane], f1 = fr[lane + 64];
    float sv = f0 * wl[b * DIM + lane] + f1 * wl[b * DIM + lane + 64];
    float rv = f0 * wr[b * DIM + lane] + f1 * wr[b * DIM + lane + 64];
#pragma unroll
    for (int off = 32; off > 0; off >>= 1) {
        sv += __shfl_down(sv, off, 64);
        rv += __shfl_down(rv, off, 64);
    }
    if (lane == 0) {
        a_self[b * N_NODES + n] = sv;
        a_nb[b * N_NODES + n] = rv;
    }
}

// ---------------- softmax + weighted aggregation + residual + relu ----------------
// grid (N_NODES, 2), block 64 (one wave per node).
// Lanes 0-31 consume even edges, lanes 32-63 odd edges; each lane loads float4
// (32 lanes x 16B = one 512B feat row per half-wave).
__global__ __launch_bounds__(64) void aggregate(
    const float* __restrict__ feat, const float* __restrict__ resid,
    const float* __restrict__ a_self, const float* __restrict__ a_nb,
    const int* __restrict__ rowptr, const int* __restrict__ csr_src,
    float* __restrict__ out) {
    const int n = blockIdx.x;
    const int b = blockIdx.y;
    const int lane = threadIdx.x;
    const int half = lane >> 5;
    const int ch4 = lane & 31;
    const int start = rowptr[n];
    const int end = rowptr[n + 1];

    __shared__ float eL[64];
    __shared__ int sL[64];

    const float* __restrict__ anb = a_nb + b * N_NODES;
    const float4* __restrict__ feat4 =
        reinterpret_cast<const float4*>(feat + (size_t)b * N_NODES * DIM);
    const float asl = a_self[b * N_NODES + n];

    // pass A: segment max (strided per lane, wave-reduce)
    float m = -INFINITY;
    for (int j = start + lane; j < end; j += 64) {
        float s = asl + anb[csr_src[j]];
        s = (s >= 0.f) ? s : NEG_SLOPE * s;
        m = fmaxf(m, s);
    }
#pragma unroll
    for (int off = 32; off > 0; off >>= 1) m = fmaxf(m, __shfl_xor(m, off, 64));

    // pass B: chunks of 64 edges; e computed one-per-lane, consumed 2 edges/iter
    float4 acc = {0.f, 0.f, 0.f, 0.f};
    float dpart = 0.f;
    for (int c = start; c < end; c += 64) {
        int j = c + lane;
        float e = 0.f;
        int srcj = 0;
        if (j < end) {
            srcj = csr_src[j];
            float s = asl + anb[srcj];
            s = (s >= 0.f) ? s : NEG_SLOPE * s;
            e = __expf(s - m);
        }
        dpart += e;
        __syncthreads();
        eL[lane] = e;
        sL[lane] = srcj;
        __syncthreads();
        int cnt = end - c;
        if (cnt > 64) cnt = 64;
        int iters = (cnt + 1) >> 1;
        for (int i2 = 0; i2 < iters; ++i2) {
            int i = i2 * 2 + half;  // half 0: even edge, half 1: odd edge (e=0 padded)
            float w = eL[i];
            int s2 = sL[i];
            float4 f = feat4[(size_t)s2 * 32 + ch4];
            acc.x += w * f.x;
            acc.y += w * f.y;
            acc.z += w * f.z;
            acc.w += w * f.w;
        }
    }

    // combine halves + denom reduce
    acc.x += __shfl_xor(acc.x, 32, 64);
    acc.y += __shfl_xor(acc.y, 32, 64);
    acc.z += __shfl_xor(acc.z, 32, 64);
    acc.w += __shfl_xor(acc.w, 32, 64);
    float denom = dpart;
#pragma unroll
    for (int off = 32; off > 0; off >>= 1) denom += __shfl_xor(denom, off, 64);

    if (half == 0) {
        float inv = (end > start) ? 1.f / denom : 0.f;
        float4 r = reinterpret_cast<const float4*>(
            resid + ((size_t)b * N_NODES + n) * DIM)[ch4];
        float4 o;
        o.x = fmaxf(acc.x * inv + r.x, 0.f);
        o.y = fmaxf(acc.y * inv + r.y, 0.f);
        o.z = fmaxf(acc.z * inv + r.z, 0.f);
        o.w = fmaxf(acc.w * inv + r.w, 0.f);
        reinterpret_cast<float4*>(out + (size_t)n * (2 * DIM) + b * DIM)[ch4] = o;
    }
}

// ---------------- per-graph sum pooling ----------------
__device__ int lower_bound_dev(const int* __restrict__ a, int n, int key) {
    int lo = 0, hi = n;
    while (lo < hi) {
        int mid = (lo + hi) >> 1;
        if (a[mid] < key) lo = mid + 1;
        else hi = mid;
    }
    return lo;
}

__global__ __launch_bounds__(256) void pool_graphs(
    const float* __restrict__ h, const int* __restrict__ gids,
    float* __restrict__ phis) {
    const int g = blockIdx.x;
    const int tid = threadIdx.x;
    int lo = lower_bound_dev(gids, N_NODES, g);
    int hi = lower_bound_dev(gids, N_NODES, g + 1);
    float acc = 0.f;
    for (int n = lo; n < hi; ++n) acc += h[(size_t)n * (2 * DIM) + tid];
    phis[(size_t)g * (2 * DIM) + tid] = acc;
}

extern "C" void kernel_launch(void* const* d_in, const int* in_sizes, int n_in,
                              void* d_out, int out_size, void* d_ws, size_t ws_size,
                              hipStream_t stream) {
    const float* x    = (const float*)d_in[0];
    const int* esrc   = (const int*)d_in[1];
    const int* edst   = (const int*)d_in[2];
    const int* gids   = (const int*)d_in[3];
    const float* Wfc  = (const float*)d_in[4];
    const float* bfc  = (const float*)d_in[5];
    const float* wl   = (const float*)d_in[6];
    const float* wr   = (const float*)d_in[7];
    const float* Wres = (const float*)d_in[8];
    float* out = (float*)d_out;

    char* ws = (char*)d_ws;
    float* feat    = (float*)(ws + 0);
    float* resid   = (float*)(ws + 10240000);
    float* a_self  = (float*)(ws + 20480000);
    float* a_nb    = (float*)(ws + 20560000);
    int*   deg     = (int*)(ws + 20640000);
    int*   rowptr  = (int*)(ws + 20688000);
    int*   cursor  = (int*)(ws + 20736000);
    int*   csr_src = (int*)(ws + 20784000);

    hipMemsetAsync(deg, 0, N_NODES * sizeof(int), stream);
    count_deg<<<(N_EDGES / 4 + 255) / 256, 256, 0, stream>>>((const int4*)edst, deg);
    scan_deg<<<1, 1024, 0, stream>>>(deg, rowptr, cursor);
    scatter_edges<<<(N_EDGES / 4 + 255) / 256, 256, 0, stream>>>(
        (const int4*)esrc, (const int4*)edst, cursor, csr_src);

    gemm_xwT<<<dim3((N_NODES + 63) / 64, 2, 4), 256, 0, stream>>>(x, Wfc, bfc, Wres, feat, resid);
    a_compute<<<dim3((N_NODES + 3) / 4, 2), 256, 0, stream>>>(feat, wl, wr, a_self, a_nb);
    aggregate<<<dim3(N_NODES, 2), 64, 0, stream>>>(feat, resid, a_self, a_nb, rowptr, csr_src, out);
    pool_graphs<<<N_GRAPHS, 256, 0, stream>>>(out, gids, out + (size_t)N_NODES * 2 * DIM);
}

// Round 3
// 237.954 us; speedup vs baseline: 1.2366x; 1.2131x over previous
//
#include <hip/hip_runtime.h>
#include <hip/hip_bf16.h>
#include <math.h>

#define N_NODES 10000
#define N_EDGES 640000
#define N_GRAPHS 64
#define DIM 128
#define NEG_SLOPE 0.01f

// ---------------- workspace layout (bytes) ----------------
// feat     : 0          .. 10,240,000   float[2][10000][128]
// resid    : 10,240,000 .. 20,480,000   float[2][10000][128]
// a_self   : 20,480,000                 float[2][10000]
// a_nb     : 20,560,000                 float[2][10000]
// deg      : 20,640,000                 int[10000]
// rowptr   : 20,688,000                 int[10001]
// cursor   : 20,736,000                 int[10000]
// csr_src  : 20,784,000                 int[640000]
// feat_b16 : 23,344,000 .. 28,464,000   bf16[2][10000][128]

// ---------------- CSR build ----------------
__global__ void count_deg(const int4* __restrict__ edst4, int* __restrict__ deg) {
    int t = blockIdx.x * blockDim.x + threadIdx.x;
    if (t < N_EDGES / 4) {
        int4 d = edst4[t];
        atomicAdd(&deg[d.x], 1);
        atomicAdd(&deg[d.y], 1);
        atomicAdd(&deg[d.z], 1);
        atomicAdd(&deg[d.w], 1);
    }
}

__global__ __launch_bounds__(1024) void scan_deg(const int* __restrict__ deg,
                                                 int* __restrict__ rowptr,
                                                 int* __restrict__ cursor) {
    __shared__ int sdata[1024];
    const int tid = threadIdx.x;
    const int base = tid * 10;
    int cnt = N_NODES - base;
    if (cnt < 0) cnt = 0;
    if (cnt > 10) cnt = 10;
    int local[10];
    int s = 0;
    for (int i = 0; i < cnt; ++i) { local[i] = s; s += deg[base + i]; }
    sdata[tid] = s;
    __syncthreads();
    for (int off = 1; off < 1024; off <<= 1) {
        int v = 0;
        if (tid >= off) v = sdata[tid - off];
        __syncthreads();
        if (tid >= off) sdata[tid] += v;
        __syncthreads();
    }
    int pre = (tid == 0) ? 0 : sdata[tid - 1];
    for (int i = 0; i < cnt; ++i) {
        int v = pre + local[i];
        rowptr[base + i] = v;
        cursor[base + i] = v;
    }
    if (tid == 1023) rowptr[N_NODES] = sdata[1023];
}

__global__ void scatter_edges(const int4* __restrict__ esrc4, const int4* __restrict__ edst4,
                              int* __restrict__ cursor, int* __restrict__ csr_src) {
    int t = blockIdx.x * blockDim.x + threadIdx.x;
    if (t < N_EDGES / 4) {
        int4 s = esrc4[t];
        int4 d = edst4[t];
        csr_src[atomicAdd(&cursor[d.x], 1)] = s.x;
        csr_src[atomicAdd(&cursor[d.y], 1)] = s.y;
        csr_src[atomicAdd(&cursor[d.z], 1)] = s.z;
        csr_src[atomicAdd(&cursor[d.w], 1)] = s.w;
    }
}

// ---------------- GEMM: out[n][j] = sum_k x[n][k]*W[j][k] (+bias) ----------------
// grid (ceil(N/64), 2, 4), block 256.  z: bit0 = which (0=feat,1=resid), bit1 = gat block
__device__ __forceinline__ unsigned short f2bf(float f) {
    __hip_bfloat16 h = __float2bfloat16(f);
    return *reinterpret_cast<unsigned short*>(&h);
}

__global__ __launch_bounds__(256) void gemm_xwT(
    const float* __restrict__ x, const float* __restrict__ Wfc,
    const float* __restrict__ bfc, const float* __restrict__ Wres,
    float* __restrict__ feat, float* __restrict__ resid,
    unsigned short* __restrict__ feat_b16) {
    const int which = blockIdx.z & 1;
    const int b = blockIdx.z >> 1;
    const float* __restrict__ W = (which ? Wres : Wfc) + b * DIM * DIM;
    float* __restrict__ out = (which ? resid : feat) + (size_t)b * N_NODES * DIM;
    const int n0 = blockIdx.x * 64;
    const int j0 = blockIdx.y * 64;

    __shared__ float xs[32][68];
    __shared__ float wsh[32][68];

    const int t = threadIdx.x;
    const int tj = t & 15;
    const int tn = t >> 4;
    const int r = t >> 2;
    const int q = t & 3;

    float acc[4][4];
#pragma unroll
    for (int i = 0; i < 4; ++i)
#pragma unroll
        for (int j = 0; j < 4; ++j) acc[i][j] = 0.f;

    for (int kc = 0; kc < DIM; kc += 32) {
        {
            float v[8];
            int n = n0 + r;
            if (n < N_NODES) {
                const float* p = x + (size_t)n * DIM + kc + q * 8;
                float4 v0 = *reinterpret_cast<const float4*>(p);
                float4 v1 = *reinterpret_cast<const float4*>(p + 4);
                v[0] = v0.x; v[1] = v0.y; v[2] = v0.z; v[3] = v0.w;
                v[4] = v1.x; v[5] = v1.y; v[6] = v1.z; v[7] = v1.w;
            } else {
#pragma unroll
                for (int m = 0; m < 8; ++m) v[m] = 0.f;
            }
#pragma unroll
            for (int m = 0; m < 8; ++m) xs[q * 8 + m][r] = v[m];

            const float* pw = W + (size_t)(j0 + r) * DIM + kc + q * 8;
            float4 w0 = *reinterpret_cast<const float4*>(pw);
            float4 w1 = *reinterpret_cast<const float4*>(pw + 4);
            float wv[8] = {w0.x, w0.y, w0.z, w0.w, w1.x, w1.y, w1.z, w1.w};
#pragma unroll
            for (int m = 0; m < 8; ++m) wsh[q * 8 + m][r] = wv[m];
        }
        __syncthreads();

#pragma unroll
        for (int k = 0; k < 32; ++k) {
            float4 xv = *reinterpret_cast<const float4*>(&xs[k][4 * tn]);
            float4 wv = *reinterpret_cast<const float4*>(&wsh[k][4 * tj]);
            float xa[4] = {xv.x, xv.y, xv.z, xv.w};
            float wa[4] = {wv.x, wv.y, wv.z, wv.w};
#pragma unroll
            for (int i = 0; i < 4; ++i)
#pragma unroll
                for (int j = 0; j < 4; ++j) acc[i][j] += xa[i] * wa[j];
        }
        __syncthreads();
    }

#pragma unroll
    for (int i = 0; i < 4; ++i) {
        int n = n0 + tn * 4 + i;
        if (n < N_NODES) {
            int j = j0 + tj * 4;
            float4 o;
            o.x = acc[i][0]; o.y = acc[i][1]; o.z = acc[i][2]; o.w = acc[i][3];
            if (!which) {
                const float* bias = bfc + b * DIM + j;
                o.x += bias[0]; o.y += bias[1]; o.z += bias[2]; o.w += bias[3];
            }
            *reinterpret_cast<float4*>(out + (size_t)n * DIM + j) = o;
            if (!which) {
                ushort4 u;
                u.x = f2bf(o.x); u.y = f2bf(o.y); u.z = f2bf(o.z); u.w = f2bf(o.w);
                *reinterpret_cast<ushort4*>(
                    feat_b16 + ((size_t)b * N_NODES + n) * DIM + j) = u;
            }
        }
    }
}

// ---------------- per-node attention scalars ----------------
__global__ __launch_bounds__(256) void a_compute(
    const float* __restrict__ feat, const float* __restrict__ wl,
    const float* __restrict__ wr, float* __restrict__ a_self,
    float* __restrict__ a_nb) {
    const int wave = threadIdx.x >> 6;
    const int lane = threadIdx.x & 63;
    const int n = blockIdx.x * 4 + wave;
    const int b = blockIdx.y;
    if (n >= N_NODES) return;
    const float* fr = feat + ((size_t)b * N_NODES + n) * DIM;
    float f0 = fr[lane], f1 = fr[lane + 64];
    float sv = f0 * wl[b * DIM + lane] + f1 * wl[b * DIM + lane + 64];
    float rv = f0 * wr[b * DIM + lane] + f1 * wr[b * DIM + lane + 64];
#pragma unroll
    for (int off = 32; off > 0; off >>= 1) {
        sv += __shfl_down(sv, off, 64);
        rv += __shfl_down(rv, off, 64);
    }
    if (lane == 0) {
        a_self[b * N_NODES + n] = sv;
        a_nb[b * N_NODES + n] = rv;
    }
}

// ---------------- softmax + weighted aggregation + residual + relu ----------------
// grid (2500, 2), block 256 = 4 waves, one node per wave.
// bf16 feat rows are 256B; quarter-wave (16 lanes x uint4) loads one full row,
// so 4 edges per wave-iteration. shfl-broadcast (no LDS, no barriers),
// software-pipelined gather (2 in flight).
__global__ __launch_bounds__(256) void aggregate(
    const unsigned short* __restrict__ feat_b16, const float* __restrict__ resid,
    const float* __restrict__ a_self, const float* __restrict__ a_nb,
    const int* __restrict__ rowptr, const int* __restrict__ csr_src,
    float* __restrict__ out) {
    const int wave = threadIdx.x >> 6;
    const int lane = threadIdx.x & 63;
    const int n = blockIdx.x * 4 + wave;
    const int b = blockIdx.y;
    const int q = lane >> 4;     // edge slot within group of 4
    const int l16 = lane & 15;   // covers channels [l16*8, l16*8+8)
    const int start = rowptr[n];
    const int end = rowptr[n + 1];

    const float* __restrict__ anb = a_nb + b * N_NODES;
    const uint4* __restrict__ fb =
        reinterpret_cast<const uint4*>(feat_b16 + (size_t)b * N_NODES * DIM);
    const float asl = a_self[b * N_NODES + n];

    // pass A: segment max
    float m = -INFINITY;
    for (int j = start + lane; j < end; j += 64) {
        float s = asl + anb[csr_src[j]];
        s = (s >= 0.f) ? s : NEG_SLOPE * s;
        m = fmaxf(m, s);
    }
#pragma unroll
    for (int off = 32; off > 0; off >>= 1) m = fmaxf(m, __shfl_xor(m, off, 64));

    float acc[8];
#pragma unroll
    for (int k = 0; k < 8; ++k) acc[k] = 0.f;
    float dpart = 0.f;

    for (int c = start; c < end; c += 64) {
        int j = c + lane;
        float e = 0.f;
        int src = 0;
        if (j < end) {
            src = csr_src[j];
            float s = asl + anb[src];
            s = (s >= 0.f) ? s : NEG_SLOPE * s;
            e = __expf(s - m);
        }
        dpart += e;
        int cnt = end - c;
        if (cnt > 64) cnt = 64;
        int iters = (cnt + 3) >> 2;

        // pipeline prologue
        float w0 = __shfl(e, q, 64);
        int s0 = __shfl(src, q, 64);
        uint4 f0 = fb[(size_t)s0 * 16 + l16];

        for (int i2 = 0; i2 < iters - 1; ++i2) {
            int idx = (i2 + 1) * 4 + q;
            float w1 = __shfl(e, idx, 64);
            int s1 = __shfl(src, idx, 64);
            uint4 f1 = fb[(size_t)s1 * 16 + l16];
#pragma unroll
            for (int k = 0; k < 4; ++k) {
                unsigned int u = (&f0.x)[k];
                float lo = __uint_as_float(u << 16);
                float hi = __uint_as_float(u & 0xffff0000u);
                acc[2 * k]     += w0 * lo;
                acc[2 * k + 1] += w0 * hi;
            }
            w0 = w1; f0 = f1;
        }
#pragma unroll
        for (int k = 0; k < 4; ++k) {
            unsigned int u = (&f0.x)[k];
            float lo = __uint_as_float(u << 16);
            float hi = __uint_as_float(u & 0xffff0000u);
            acc[2 * k]     += w0 * lo;
            acc[2 * k + 1] += w0 * hi;
        }
    }

    // reduce the 4 edge-slots (lanes l16, l16+16, l16+32, l16+48 share channels)
#pragma unroll
    for (int k = 0; k < 8; ++k) {
        acc[k] += __shfl_xor(acc[k], 16, 64);
        acc[k] += __shfl_xor(acc[k], 32, 64);
    }
    float denom = dpart;
#pragma unroll
    for (int off = 32; off > 0; off >>= 1) denom += __shfl_xor(denom, off, 64);

    if (q == 0) {
        float inv = (end > start) ? 1.f / denom : 0.f;
        const float4* rr = reinterpret_cast<const float4*>(
            resid + ((size_t)b * N_NODES + n) * DIM);
        float4 r0 = rr[l16 * 2];
        float4 r1 = rr[l16 * 2 + 1];
        float4 o0, o1;
        o0.x = fmaxf(acc[0] * inv + r0.x, 0.f);
        o0.y = fmaxf(acc[1] * inv + r0.y, 0.f);
        o0.z = fmaxf(acc[2] * inv + r0.z, 0.f);
        o0.w = fmaxf(acc[3] * inv + r0.w, 0.f);
        o1.x = fmaxf(acc[4] * inv + r1.x, 0.f);
        o1.y = fmaxf(acc[5] * inv + r1.y, 0.f);
        o1.z = fmaxf(acc[6] * inv + r1.z, 0.f);
        o1.w = fmaxf(acc[7] * inv + r1.w, 0.f);
        float4* po = reinterpret_cast<float4*>(out + (size_t)n * (2 * DIM) + b * DIM);
        po[l16 * 2] = o0;
        po[l16 * 2 + 1] = o1;
    }
}

// ---------------- per-graph sum pooling ----------------
__device__ int lower_bound_dev(const int* __restrict__ a, int n, int key) {
    int lo = 0, hi = n;
    while (lo < hi) {
        int mid = (lo + hi) >> 1;
        if (a[mid] < key) lo = mid + 1;
        else hi = mid;
    }
    return lo;
}

// grid (N_GRAPHS, 16), block 256; partial sums + atomicAdd into zeroed phis
__global__ __launch_bounds__(256) void pool_graphs(
    const float* __restrict__ h, const int* __restrict__ gids,
    float* __restrict__ phis) {
    const int g = blockIdx.x;
    const int chunk = blockIdx.y;
    const int tid = threadIdx.x;
    int lo = lower_bound_dev(gids, N_NODES, g);
    int hi = lower_bound_dev(gids, N_NODES, g + 1);
    float acc = 0.f;
    for (int n = lo + chunk; n < hi; n += 16) acc += h[(size_t)n * (2 * DIM) + tid];
    if (acc != 0.f) atomicAdd(&phis[(size_t)g * (2 * DIM) + tid], acc);
}

extern "C" void kernel_launch(void* const* d_in, const int* in_sizes, int n_in,
                              void* d_out, int out_size, void* d_ws, size_t ws_size,
                              hipStream_t stream) {
    const float* x    = (const float*)d_in[0];
    const int* esrc   = (const int*)d_in[1];
    const int* edst   = (const int*)d_in[2];
    const int* gids   = (const int*)d_in[3];
    const float* Wfc  = (const float*)d_in[4];
    const float* bfc  = (const float*)d_in[5];
    const float* wl   = (const float*)d_in[6];
    const float* wr   = (const float*)d_in[7];
    const float* Wres = (const float*)d_in[8];
    float* out = (float*)d_out;

    char* ws = (char*)d_ws;
    float* feat    = (float*)(ws + 0);
    float* resid   = (float*)(ws + 10240000);
    float* a_self  = (float*)(ws + 20480000);
    float* a_nb    = (float*)(ws + 20560000);
    int*   deg     = (int*)(ws + 20640000);
    int*   rowptr  = (int*)(ws + 20688000);
    int*   cursor  = (int*)(ws + 20736000);
    int*   csr_src = (int*)(ws + 20784000);
    unsigned short* feat_b16 = (unsigned short*)(ws + 23344000);

    float* phis = out + (size_t)N_NODES * 2 * DIM;

    hipMemsetAsync(deg, 0, N_NODES * sizeof(int), stream);
    hipMemsetAsync(phis, 0, N_GRAPHS * 2 * DIM * sizeof(float), stream);

    count_deg<<<(N_EDGES / 4 + 255) / 256, 256, 0, stream>>>((const int4*)edst, deg);
    scan_deg<<<1, 1024, 0, stream>>>(deg, rowptr, cursor);
    scatter_edges<<<(N_EDGES / 4 + 255) / 256, 256, 0, stream>>>(
        (const int4*)esrc, (const int4*)edst, cursor, csr_src);

    gemm_xwT<<<dim3((N_NODES + 63) / 64, 2, 4), 256, 0, stream>>>(
        x, Wfc, bfc, Wres, feat, resid, feat_b16);
    a_compute<<<dim3((N_NODES + 3) / 4, 2), 256, 0, stream>>>(feat, wl, wr, a_self, a_nb);
    aggregate<<<dim3(2500, 2), 256, 0, stream>>>(
        feat_b16, resid, a_self, a_nb, rowptr, csr_src, out);
    pool_graphs<<<dim3(N_GRAPHS, 16), 256, 0, stream>>>(out, gids, phis);
}

// Round 4
// 167.509 us; speedup vs baseline: 1.7567x; 1.4205x over previous
//
#include <hip/hip_runtime.h>
#include <hip/hip_bf16.h>
#include <math.h>

#define N_NODES 10000
#define N_EDGES 640000
#define N_GRAPHS 64
#define DIM 128
#define NEG_SLOPE 0.01f
#define NB_CSR 128            // histogram partitions (5000 edges each)
#define EDGES_PER_BLK (N_EDGES / NB_CSR)

// ---------------- workspace layout (bytes) ----------------
// feat     : 0          .. 10,240,000   float[2][10000][128]
// resid    : 10,240,000 .. 20,480,000   float[2][10000][128]
// a_self   : 20,480,000                 float[2][10000]
// a_nb     : 20,560,000                 float[2][10000]
// deg      : 20,640,000                 int[10000]
// rowptr   : 20,688,000                 int[10001]
// csr_src  : 20,784,000                 int[640000]
// feat_b16 : 23,344,000 .. 28,464,000   bf16[2][10000][128]
// bh       : 28,464,000 .. 33,584,000   int[128][10000] (hist -> in-place excl. offsets)

// ---------------- CSR build: phase 1, per-partition LDS histogram ----------------
__global__ __launch_bounds__(512) void csr_hist(const int4* __restrict__ edst4,
                                                int* __restrict__ bh) {
    __shared__ int hist[N_NODES];
    const int blk = blockIdx.x;
    const int t = threadIdx.x;
    for (int n = t; n < N_NODES; n += 512) hist[n] = 0;
    __syncthreads();
    const int base4 = blk * (EDGES_PER_BLK / 4);
    for (int i = t; i < EDGES_PER_BLK / 4; i += 512) {
        int4 d = edst4[base4 + i];
        atomicAdd(&hist[d.x], 1);
        atomicAdd(&hist[d.y], 1);
        atomicAdd(&hist[d.z], 1);
        atomicAdd(&hist[d.w], 1);
    }
    __syncthreads();
    int* dst = bh + (size_t)blk * N_NODES;
    for (int n = t; n < N_NODES; n += 512) dst[n] = hist[n];
}

// ---------------- CSR build: phase 2, per-node scan over partitions ----------------
// bh[blk][n] becomes exclusive prefix (within node n, over blk); deg[n] = total.
__global__ __launch_bounds__(256) void csr_node_scan(int* __restrict__ bh,
                                                     int* __restrict__ deg) {
    int n = blockIdx.x * 256 + threadIdx.x;
    if (n >= N_NODES) return;
    int running = 0;
    for (int blk = 0; blk < NB_CSR; ++blk) {
        int* p = bh + (size_t)blk * N_NODES + n;
        int v = *p;
        *p = running;
        running += v;
    }
    deg[n] = running;
}

// ---------------- CSR build: phase 3, rowptr scan ----------------
__global__ __launch_bounds__(1024) void scan_deg(const int* __restrict__ deg,
                                                 int* __restrict__ rowptr) {
    __shared__ int sdata[1024];
    const int tid = threadIdx.x;
    const int base = tid * 10;
    int cnt = N_NODES - base;
    if (cnt < 0) cnt = 0;
    if (cnt > 10) cnt = 10;
    int local[10];
    int s = 0;
    for (int i = 0; i < cnt; ++i) { local[i] = s; s += deg[base + i]; }
    sdata[tid] = s;
    __syncthreads();
    for (int off = 1; off < 1024; off <<= 1) {
        int v = 0;
        if (tid >= off) v = sdata[tid - off];
        __syncthreads();
        if (tid >= off) sdata[tid] += v;
        __syncthreads();
    }
    int pre = (tid == 0) ? 0 : sdata[tid - 1];
    for (int i = 0; i < cnt; ++i) rowptr[base + i] = pre + local[i];
    if (tid == 1023) rowptr[N_NODES] = sdata[1023];
}

// ---------------- CSR build: phase 4, scatter via LDS cursors ----------------
__global__ __launch_bounds__(512) void csr_scatter(
    const int4* __restrict__ esrc4, const int4* __restrict__ edst4,
    const int* __restrict__ rowptr, const int* __restrict__ bh,
    int* __restrict__ csr_src) {
    __shared__ int cur[N_NODES];
    const int blk = blockIdx.x;
    const int t = threadIdx.x;
    const int* boff = bh + (size_t)blk * N_NODES;
    for (int n = t; n < N_NODES; n += 512) cur[n] = rowptr[n] + boff[n];
    __syncthreads();
    const int base4 = blk * (EDGES_PER_BLK / 4);
    for (int i = t; i < EDGES_PER_BLK / 4; i += 512) {
        int4 s = esrc4[base4 + i];
        int4 d = edst4[base4 + i];
        csr_src[atomicAdd(&cur[d.x], 1)] = s.x;
        csr_src[atomicAdd(&cur[d.y], 1)] = s.y;
        csr_src[atomicAdd(&cur[d.z], 1)] = s.z;
        csr_src[atomicAdd(&cur[d.w], 1)] = s.w;
    }
}

// ---------------- GEMM: out[n][j] = sum_k x[n][k]*W[j][k] (+bias) ----------------
// grid (ceil(N/64), 2, 4), block 256.  z: bit0 = which (0=feat,1=resid), bit1 = gat block
// which==0 epilogue also emits bf16 feat + partial a_self/a_nb via atomics.
__device__ __forceinline__ unsigned short f2bf(float f) {
    __hip_bfloat16 h = __float2bfloat16(f);
    return *reinterpret_cast<unsigned short*>(&h);
}

__global__ __launch_bounds__(256) void gemm_xwT(
    const float* __restrict__ x, const float* __restrict__ Wfc,
    const float* __restrict__ bfc, const float* __restrict__ Wres,
    float* __restrict__ feat, float* __restrict__ resid,
    unsigned short* __restrict__ feat_b16,
    const float* __restrict__ wl, const float* __restrict__ wr,
    float* __restrict__ a_self, float* __restrict__ a_nb) {
    const int which = blockIdx.z & 1;
    const int b = blockIdx.z >> 1;
    const float* __restrict__ W = (which ? Wres : Wfc) + b * DIM * DIM;
    float* __restrict__ out = (which ? resid : feat) + (size_t)b * N_NODES * DIM;
    const int n0 = blockIdx.x * 64;
    const int j0 = blockIdx.y * 64;

    __shared__ float xs[32][68];
    __shared__ float wsh[32][68];

    const int t = threadIdx.x;
    const int tj = t & 15;
    const int tn = t >> 4;
    const int r = t >> 2;
    const int q = t & 3;

    float acc[4][4];
#pragma unroll
    for (int i = 0; i < 4; ++i)
#pragma unroll
        for (int j = 0; j < 4; ++j) acc[i][j] = 0.f;

    for (int kc = 0; kc < DIM; kc += 32) {
        {
            float v[8];
            int n = n0 + r;
            if (n < N_NODES) {
                const float* p = x + (size_t)n * DIM + kc + q * 8;
                float4 v0 = *reinterpret_cast<const float4*>(p);
                float4 v1 = *reinterpret_cast<const float4*>(p + 4);
                v[0] = v0.x; v[1] = v0.y; v[2] = v0.z; v[3] = v0.w;
                v[4] = v1.x; v[5] = v1.y; v[6] = v1.z; v[7] = v1.w;
            } else {
#pragma unroll
                for (int m = 0; m < 8; ++m) v[m] = 0.f;
            }
#pragma unroll
            for (int m = 0; m < 8; ++m) xs[q * 8 + m][r] = v[m];

            const float* pw = W + (size_t)(j0 + r) * DIM + kc + q * 8;
            float4 w0 = *reinterpret_cast<const float4*>(pw);
            float4 w1 = *reinterpret_cast<const float4*>(pw + 4);
            float wv[8] = {w0.x, w0.y, w0.z, w0.w, w1.x, w1.y, w1.z, w1.w};
#pragma unroll
            for (int m = 0; m < 8; ++m) wsh[q * 8 + m][r] = wv[m];
        }
        __syncthreads();

#pragma unroll
        for (int k = 0; k < 32; ++k) {
            float4 xv = *reinterpret_cast<const float4*>(&xs[k][4 * tn]);
            float4 wv = *reinterpret_cast<const float4*>(&wsh[k][4 * tj]);
            float xa[4] = {xv.x, xv.y, xv.z, xv.w};
            float wa[4] = {wv.x, wv.y, wv.z, wv.w};
#pragma unroll
            for (int i = 0; i < 4; ++i)
#pragma unroll
                for (int j = 0; j < 4; ++j) acc[i][j] += xa[i] * wa[j];
        }
        __syncthreads();
    }

    float wlv[4], wrv[4];
    if (!which) {
#pragma unroll
        for (int k = 0; k < 4; ++k) {
            wlv[k] = wl[b * DIM + j0 + tj * 4 + k];
            wrv[k] = wr[b * DIM + j0 + tj * 4 + k];
        }
    }

#pragma unroll
    for (int i = 0; i < 4; ++i) {
        int n = n0 + tn * 4 + i;
        int j = j0 + tj * 4;
        float4 o;
        o.x = acc[i][0]; o.y = acc[i][1]; o.z = acc[i][2]; o.w = acc[i][3];
        if (!which) {
            const float* bias = bfc + b * DIM + j;
            o.x += bias[0]; o.y += bias[1]; o.z += bias[2]; o.w += bias[3];
        }
        if (n < N_NODES) {
            *reinterpret_cast<float4*>(out + (size_t)n * DIM + j) = o;
            if (!which) {
                ushort4 u;
                u.x = f2bf(o.x); u.y = f2bf(o.y); u.z = f2bf(o.z); u.w = f2bf(o.w);
                *reinterpret_cast<ushort4*>(
                    feat_b16 + ((size_t)b * N_NODES + n) * DIM + j) = u;
            }
        }
        if (!which) {
            // partial attention scalars over this block's 64 j-channels
            float ps = o.x * wlv[0] + o.y * wlv[1] + o.z * wlv[2] + o.w * wlv[3];
            float pr = o.x * wrv[0] + o.y * wrv[1] + o.z * wrv[2] + o.w * wrv[3];
#pragma unroll
            for (int off = 8; off > 0; off >>= 1) {
                ps += __shfl_xor(ps, off, 64);
                pr += __shfl_xor(pr, off, 64);
            }
            if (tj == 0 && n < N_NODES) {
                atomicAdd(&a_self[b * N_NODES + n], ps);
                atomicAdd(&a_nb[b * N_NODES + n], pr);
            }
        }
    }
}

// ---------------- softmax + weighted aggregation + residual + relu ----------------
// grid (2500, 2), block 256 = 4 waves, one node per wave. Single pass (no max:
// scores bounded ~|s|<20 << 88, exp(s) safe in fp32; softmax shift-invariant).
__global__ __launch_bounds__(256) void aggregate(
    const unsigned short* __restrict__ feat_b16, const float* __restrict__ resid,
    const float* __restrict__ a_self, const float* __restrict__ a_nb,
    const int* __restrict__ rowptr, const int* __restrict__ csr_src,
    float* __restrict__ out) {
    const int wave = threadIdx.x >> 6;
    const int lane = threadIdx.x & 63;
    const int n = blockIdx.x * 4 + wave;
    const int b = blockIdx.y;
    const int q = lane >> 4;     // edge slot within group of 4
    const int l16 = lane & 15;   // covers channels [l16*8, l16*8+8)
    const int start = rowptr[n];
    const int end = rowptr[n + 1];

    const float* __restrict__ anb = a_nb + b * N_NODES;
    const uint4* __restrict__ fb =
        reinterpret_cast<const uint4*>(feat_b16 + (size_t)b * N_NODES * DIM);
    const float asl = a_self[b * N_NODES + n];

    float acc[8];
#pragma unroll
    for (int k = 0; k < 8; ++k) acc[k] = 0.f;
    float dpart = 0.f;

    for (int c = start; c < end; c += 64) {
        int j = c + lane;
        float e = 0.f;
        int src = 0;
        if (j < end) {
            src = csr_src[j];
            float s = asl + anb[src];
            s = (s >= 0.f) ? s : NEG_SLOPE * s;
            e = __expf(s);
        }
        dpart += e;
        int cnt = end - c;
        if (cnt > 64) cnt = 64;
        int iters = (cnt + 3) >> 2;

        float w0 = __shfl(e, q, 64);
        int s0 = __shfl(src, q, 64);
        uint4 f0 = fb[(size_t)s0 * 16 + l16];

        for (int i2 = 0; i2 < iters - 1; ++i2) {
            int idx = (i2 + 1) * 4 + q;
            float w1 = __shfl(e, idx, 64);
            int s1 = __shfl(src, idx, 64);
            uint4 f1 = fb[(size_t)s1 * 16 + l16];
#pragma unroll
            for (int k = 0; k < 4; ++k) {
                unsigned int u = (&f0.x)[k];
                float lo = __uint_as_float(u << 16);
                float hi = __uint_as_float(u & 0xffff0000u);
                acc[2 * k]     += w0 * lo;
                acc[2 * k + 1] += w0 * hi;
            }
            w0 = w1; f0 = f1;
        }
#pragma unroll
        for (int k = 0; k < 4; ++k) {
            unsigned int u = (&f0.x)[k];
            float lo = __uint_as_float(u << 16);
            float hi = __uint_as_float(u & 0xffff0000u);
            acc[2 * k]     += w0 * lo;
            acc[2 * k + 1] += w0 * hi;
        }
    }

#pragma unroll
    for (int k = 0; k < 8; ++k) {
        acc[k] += __shfl_xor(acc[k], 16, 64);
        acc[k] += __shfl_xor(acc[k], 32, 64);
    }
    float denom = dpart;
#pragma unroll
    for (int off = 32; off > 0; off >>= 1) denom += __shfl_xor(denom, off, 64);

    if (q == 0) {
        float inv = (end > start) ? 1.f / denom : 0.f;
        const float4* rr = reinterpret_cast<const float4*>(
            resid + ((size_t)b * N_NODES + n) * DIM);
        float4 r0 = rr[l16 * 2];
        float4 r1 = rr[l16 * 2 + 1];
        float4 o0, o1;
        o0.x = fmaxf(acc[0] * inv + r0.x, 0.f);
        o0.y = fmaxf(acc[1] * inv + r0.y, 0.f);
        o0.z = fmaxf(acc[2] * inv + r0.z, 0.f);
        o0.w = fmaxf(acc[3] * inv + r0.w, 0.f);
        o1.x = fmaxf(acc[4] * inv + r1.x, 0.f);
        o1.y = fmaxf(acc[5] * inv + r1.y, 0.f);
        o1.z = fmaxf(acc[6] * inv + r1.z, 0.f);
        o1.w = fmaxf(acc[7] * inv + r1.w, 0.f);
        float4* po = reinterpret_cast<float4*>(out + (size_t)n * (2 * DIM) + b * DIM);
        po[l16 * 2] = o0;
        po[l16 * 2 + 1] = o1;
    }
}

// ---------------- per-graph sum pooling ----------------
__device__ int lower_bound_dev(const int* __restrict__ a, int n, int key) {
    int lo = 0, hi = n;
    while (lo < hi) {
        int mid = (lo + hi) >> 1;
        if (a[mid] < key) lo = mid + 1;
        else hi = mid;
    }
    return lo;
}

__global__ __launch_bounds__(256) void pool_graphs(
    const float* __restrict__ h, const int* __restrict__ gids,
    float* __restrict__ phis) {
    const int g = blockIdx.x;
    const int chunk = blockIdx.y;
    const int tid = threadIdx.x;
    int lo = lower_bound_dev(gids, N_NODES, g);
    int hi = lower_bound_dev(gids, N_NODES, g + 1);
    float acc = 0.f;
    for (int n = lo + chunk; n < hi; n += 16) acc += h[(size_t)n * (2 * DIM) + tid];
    if (acc != 0.f) atomicAdd(&phis[(size_t)g * (2 * DIM) + tid], acc);
}

extern "C" void kernel_launch(void* const* d_in, const int* in_sizes, int n_in,
                              void* d_out, int out_size, void* d_ws, size_t ws_size,
                              hipStream_t stream) {
    const float* x    = (const float*)d_in[0];
    const int* esrc   = (const int*)d_in[1];
    const int* edst   = (const int*)d_in[2];
    const int* gids   = (const int*)d_in[3];
    const float* Wfc  = (const float*)d_in[4];
    const float* bfc  = (const float*)d_in[5];
    const float* wl   = (const float*)d_in[6];
    const float* wr   = (const float*)d_in[7];
    const float* Wres = (const float*)d_in[8];
    float* out = (float*)d_out;

    char* ws = (char*)d_ws;
    float* feat    = (float*)(ws + 0);
    float* resid   = (float*)(ws + 10240000);
    float* a_self  = (float*)(ws + 20480000);
    float* a_nb    = (float*)(ws + 20560000);
    int*   deg     = (int*)(ws + 20640000);
    int*   rowptr  = (int*)(ws + 20688000);
    int*   csr_src = (int*)(ws + 20784000);
    unsigned short* feat_b16 = (unsigned short*)(ws + 23344000);
    int*   bh      = (int*)(ws + 28464000);

    float* phis = out + (size_t)N_NODES * 2 * DIM;

    // zero a_self+a_nb (contiguous 160KB) and phis
    hipMemsetAsync(a_self, 0, 4 * N_NODES * sizeof(float), stream);
    hipMemsetAsync(phis, 0, N_GRAPHS * 2 * DIM * sizeof(float), stream);

    csr_hist<<<NB_CSR, 512, 0, stream>>>((const int4*)edst, bh);
    csr_node_scan<<<(N_NODES + 255) / 256, 256, 0, stream>>>(bh, deg);
    scan_deg<<<1, 1024, 0, stream>>>(deg, rowptr);
    csr_scatter<<<NB_CSR, 512, 0, stream>>>(
        (const int4*)esrc, (const int4*)edst, rowptr, bh, csr_src);

    gemm_xwT<<<dim3((N_NODES + 63) / 64, 2, 4), 256, 0, stream>>>(
        x, Wfc, bfc, Wres, feat, resid, feat_b16, wl, wr, a_self, a_nb);
    aggregate<<<dim3(2500, 2), 256, 0, stream>>>(
        feat_b16, resid, a_self, a_nb, rowptr, csr_src, out);
    pool_graphs<<<dim3(N_GRAPHS, 16), 256, 0, stream>>>(out, gids, phis);
}